// Round 1
// baseline (8913.375 us; speedup 1.0000x reference)
//
#include <hip/hip_runtime.h>

typedef _Float16 f16;
typedef _Float16 f16x8 __attribute__((ext_vector_type(8)));
typedef float f32x4 __attribute__((ext_vector_type(4)));

#define BB 8
#define TT 1024
#define HH 768
#define HDD 384
#define NG 1536        // 4*HDD
#define SS 16
#define MTOT (BB*TT)   // 8192

// ---------------- casts ----------------
__global__ void cast_f32_f16_k(const float* __restrict__ src, f16* __restrict__ dst, int n) {
    int i = blockIdx.x*256 + threadIdx.x;
    if (i < n) dst[i] = (f16)src[i];
}

__global__ void bias_sum_k(const float* a0,const float* b0,const float* a1,const float* b1,
                           const float* a2,const float* b2,const float* a3,const float* b3,
                           float* __restrict__ out) {
    int i = blockIdx.x*256 + threadIdx.x;
    if (i >= 4*NG) return;
    int which = i/NG, j = i - which*NG;
    const float* pa = which==0?a0:which==1?a1:which==2?a2:a3;
    const float* pb = which==0?b0:which==1?b1:which==2?b2:b3;
    out[i] = pa[j] + pb[j];
}

__global__ void embed_cast_k(const int* __restrict__ ids, const float* __restrict__ emb,
                             f16* __restrict__ x) {
    int i = blockIdx.x*256 + threadIdx.x;   // < MTOT*HH
    if (i < MTOT*HH) {
        int m = i / HH;
        int k = i - m*HH;
        x[i] = (f16)emb[(size_t)ids[m]*HH + k];
    }
}

// ---------------- input GEMM ----------------
// R6: epilogue now writes pre in wave-chunk layout so the LSTM can bulk-stage
// it into LDS with global_load_lds:
//   pre[dir][wb][t][lc][b][gate], wb=c/16 (0..23), lc=c%16, b=batch, gate=0..3
//   -> per (wb,t): 16*8*4 f16 = 1KB contiguous; per wb: 1MB contiguous.
__launch_bounds__(256,1)
__global__ void gemm_pre_k(const f16* __restrict__ A, const f16* __restrict__ Wf,
                           const f16* __restrict__ Wb, const float* __restrict__ bsum2,
                           f16* __restrict__ pre) {
    int d = blockIdx.z;
    const f16* Wt = d ? Wb : Wf;
    const float* bs = bsum2 + d*NG;
    f16* out = pre + (size_t)d*MTOT*NG;
    int m0 = blockIdx.x*64, n0 = blockIdx.y*64;
    __shared__ f16 As[64*72];
    __shared__ f16 Bs[64*72];
    int tid = threadIdx.x;
    int w = tid>>6, l = tid&63;
    int lrow = l&15, lgrp = l>>4;
    int mq = (w>>1)*32, nq = (w&1)*32;
    f32x4 acc00={0,0,0,0}, acc01={0,0,0,0}, acc10={0,0,0,0}, acc11={0,0,0,0};

    for (int k0=0; k0<HH; k0+=64) {
        __syncthreads();
        #pragma unroll
        for (int r=0;r<2;r++) {
            int c = tid + 256*r;
            int row = c>>3, seg = c&7;
            *(f16x8*)(As + row*72 + seg*8) = *(const f16x8*)(A  + ((size_t)(m0+row))*HH + k0 + seg*8);
            *(f16x8*)(Bs + row*72 + seg*8) = *(const f16x8*)(Wt + ((size_t)(n0+row))*HH + k0 + seg*8);
        }
        __syncthreads();
        #pragma unroll
        for (int kk=0; kk<64; kk+=32) {
            f16x8 a0 = *(const f16x8*)(As + (mq+lrow)*72    + kk + lgrp*8);
            f16x8 a1 = *(const f16x8*)(As + (mq+16+lrow)*72 + kk + lgrp*8);
            f16x8 b0 = *(const f16x8*)(Bs + (nq+lrow)*72    + kk + lgrp*8);
            f16x8 b1 = *(const f16x8*)(Bs + (nq+16+lrow)*72 + kk + lgrp*8);
            acc00 = __builtin_amdgcn_mfma_f32_16x16x32_f16(a0,b0,acc00,0,0,0);
            acc01 = __builtin_amdgcn_mfma_f32_16x16x32_f16(a0,b1,acc01,0,0,0);
            acc10 = __builtin_amdgcn_mfma_f32_16x16x32_f16(a1,b0,acc10,0,0,0);
            acc11 = __builtin_amdgcn_mfma_f32_16x16x32_f16(a1,b1,acc11,0,0,0);
        }
    }
    #pragma unroll
    for (int mt=0;mt<2;mt++) {
        #pragma unroll
        for (int nt=0;nt<2;nt++) {
            f32x4 a = (mt==0)?(nt==0?acc00:acc01):(nt==0?acc10:acc11);
            int col = n0 + nq + nt*16 + lrow;     // 0..1535 = gate*384 + c
            int gate = col / HDD;
            int c = col - gate*HDD;               // 0..383
            float bv = bs[col];
            size_t base = (size_t)(c>>4)*524288 + (size_t)(c&15)*32 + gate;
            #pragma unroll
            for (int r=0;r<4;r++) {
                int row = m0 + mq + mt*16 + lgrp*4 + r;   // b*1024 + t
                int b = row >> 10, t = row & 1023;
                out[base + (size_t)t*512 + b*4] = (f16)(a[r] + bv);
            }
        }
    }
}

// ---- helpers ----
__device__ __forceinline__ unsigned ld_u32_sc0(const unsigned* p) {
    unsigned v;
    asm volatile("global_load_dword %0, %1, off sc0\n\ts_waitcnt vmcnt(0)"
                 : "=v"(v) : "v"(p) : "memory");
    return v;
}
__device__ __forceinline__ unsigned get_xcc() {
    unsigned x;
    asm("s_getreg_b32 %0, hwreg(HW_REG_XCC_ID)" : "=s"(x));
    return x & 7u;
}
__device__ __forceinline__ void gload_lds16(const f16* g, f16* lds) {
    // wave-uniform LDS dest (HW adds lane*16B); per-lane global src
    __builtin_amdgcn_global_load_lds(
        (const __attribute__((address_space(1))) void*)g,
        (__attribute__((address_space(3))) void*)lds, 16, 0, 0);
}

// ---------------- LSTM recurrence ----------------
// R6: wave-owns-4-gates restructure.
//  - 12 blocks (6/dir), 4 waves each; wave owns 16 cols x all 4 gates
//    (bf[4][12] B-frags register/AGPR-resident, 192 regs).
//  - MFMA C layout puts all 4 gate pre-acts for (b,c) in one lane ->
//    in-register epilogue. ZERO __syncthreads in the step loop.
//  - per-WAVE flags (24/dir): stores -> s_waitcnt vmcnt(0) -> flag. No barrier.
//  - pre staged to LDS in per-wave 8-step/8KB double-buffered chunks via
//    global_load_lds; per-step pre access is ds_read (lgkmcnt), so the
//    sc0 poll's vmcnt(0) no longer drains HBM latency every step (only the
//    once-per-8-steps chunk issue, amortized ~1/8).
//  - election/fallback protocol identical to R5 (threshold 12, capped loops,
//    fast sc0 path + safe atomic path + sticky dead free-run).
#define EPI(r, PV, q, cstv, hhv)                                   \
    {                                                              \
        float xi = (float)PV[q*4+0] + acc0[r];                     \
        float xf = (float)PV[q*4+1] + acc1[r];                     \
        float xg = (float)PV[q*4+2] + acc2[r];                     \
        float xo = (float)PV[q*4+3] + acc3[r];                     \
        float si = 1.f/(1.f+__expf(-xi));                          \
        float sf = 1.f/(1.f+__expf(-xf));                          \
        float eg = __expf(2.f*xg); float gg = (eg-1.f)/(eg+1.f);   \
        float so = 1.f/(1.f+__expf(-xo));                          \
        cstv = sf*cstv + si*gg;                                    \
        float ec = __expf(2.f*cstv); float tc = (ec-1.f)/(ec+1.f); \
        hhv = (f16)(so*tc);                                        \
    }

#define STEX(hhv, rr)                                                       \
    {                                                                       \
        unsigned short hu; __builtin_memcpy(&hu, &hhv, 2);                  \
        unsigned short pu = (unsigned short)__shfl_xor((int)hu, 1, 64);     \
        if (lgrp < 2 && (l & 1) == 0) {                                     \
            unsigned pkt = (unsigned)hu | ((unsigned)pu << 16);             \
            *(unsigned*)(exrow + ex_wbase + (size_t)(lgrp*4 + rr)*8) = pkt; \
        }                                                                   \
    }

__launch_bounds__(256,1)
__global__ void lstm_layer_k(const f16* __restrict__ pre,
                             const f16* __restrict__ whh_f,
                             const f16* __restrict__ whh_b,
                             f16* __restrict__ xout,
                             f16* __restrict__ exch,
                             unsigned* __restrict__ flags_fast,
                             unsigned* __restrict__ flags_safe,
                             unsigned* __restrict__ elect) {
    int tid = threadIdx.x;
    __shared__ unsigned role_s;
    __shared__ f16 preS[4*2*8*512];   // 64KB: [wave][buf2][slot8][512]
    if (tid == 0) {
        unsigned xcc = get_xcc();
        unsigned r = __hip_atomic_fetch_add(&elect[xcc], 1u,
                        __ATOMIC_RELAXED, __HIP_MEMORY_SCOPE_AGENT);
        if (r == 11u) {                      // this XCD just reached 12 running blocks
            unsigned expected = 0u;
            __hip_atomic_compare_exchange_strong(&elect[8], &expected, xcc + 1u,
                __ATOMIC_RELAXED, __ATOMIC_RELAXED, __HIP_MEMORY_SCOPE_AGENT);
        }
        unsigned win = 0;
        for (int it = 0; it < (1<<20) && !win; ++it) {   // capped: no hang possible
            win = __hip_atomic_load(&elect[8], __ATOMIC_RELAXED, __HIP_MEMORY_SCOPE_AGENT);
            if (!win) __builtin_amdgcn_s_sleep(8);
        }
        unsigned role = 0xFFFFFFFFu;
        if (win == xcc + 1u)
            role = __hip_atomic_fetch_add(&elect[9], 1u,
                        __ATOMIC_RELAXED, __HIP_MEMORY_SCOPE_AGENT);
        role_s = role;
    }
    __syncthreads();
    unsigned role = role_s;
    if (role >= 12u) return;

    int dir = role >= 6u;
    int g   = (int)role - dir*6;
    const f16* W    = dir ? whh_b : whh_f;
    const f16* preD = pre  + (size_t)dir*MTOT*NG;
    f16* exchD      = exch + (size_t)dir*TT*3072;
    unsigned* ffD = flags_fast + dir*24*TT;
    unsigned* fsD = flags_safe + dir*24*TT;

    int w = tid>>6, l = tid&63;
    int lrow = l&15, lgrp = l>>4;
    int wc0  = g*64 + w*16;          // wave's 16-col slice base
    int wfid = g*4 + w;              // wave flag id / pre col-block, 0..23

    // W_hh B-frags: [gate][kk], rows = gate*384 + wc0 + {0..15}
    f16x8 bf[4][12];
    #pragma unroll
    for (int gi=0; gi<4; gi++) {
        const f16* wr = W + (size_t)(gi*HDD + wc0 + lrow)*HDD;
        #pragma unroll
        for (int kk=0; kk<12; kk++)
            bf[gi][kk] = *(const f16x8*)(wr + kk*32 + lgrp*8);
    }

    const f16* ex_base = exchD + (size_t)lgrp*64 + (size_t)lrow*8;
    const f16* srcW = preD + (size_t)wfid*524288;       // this wave's pre block
    f16* myLDS = preS + (size_t)w*(2*8*512);
    int hbq = lgrp & 1;              // batch-quad (lanes>=32 mirror, unused)
    const f16* lread = myLDS + lrow*32 + hbq*16;

    {   // prologue: stage chunk for steps 0..7
        int tmin = dir ? TT-8 : 0;
        const f16* src = srcW + (size_t)tmin*512 + l*8;
        #pragma unroll
        for (int i=0;i<8;i++)
            gload_lds16(src + i*512, myLDS + i*512);
        asm volatile("s_waitcnt vmcnt(0)" ::: "memory");
    }

    float cst0=0.f, cst1=0.f, cst2=0.f, cst3=0.f;
    int fast_ok = 1, dead = 0;       // wave-uniform sticky state
    int c = wc0 + lrow;              // this lane's output column
    size_t ex_wbase = (size_t)(c>>3)*64 + (c&7);
    size_t xo_base  = (size_t)dir*HDD + c;

    for (int step=0; step<TT; step++) {
        int t = dir ? (TT-1-step) : step;
        int slot = dir ? (7-(step&7)) : (step&7);   // LDS holds t-ascending
        int buf = (step>>3)&1;
        // pre from LDS (lgkmcnt; staged chunk guaranteed complete by the
        // vmcnt(0)s in polls of the previous 7 steps / prologue drain)
        const f16* lp = lread + buf*4096 + slot*512;
        f16x8 pA = *(const f16x8*)(lp);       // b = hbq*4+{0,1} x 4 gates
        f16x8 pB = *(const f16x8*)(lp + 8);   // b = hbq*4+{2,3} x 4 gates

        f32x4 acc0={0,0,0,0}, acc1={0,0,0,0}, acc2={0,0,0,0}, acc3={0,0,0,0};
        if (step > 0) {
            unsigned got = (l < 24) ? 0u : 1u;
            if (!dead) {
                if (fast_ok) {
                    const unsigned* fp = ffD + (size_t)l*TT + (step-1);
                    for (int it=0; it<1024 && !__all(got != 0); ++it)
                        if (!got) got = ld_u32_sc0(fp);
                    if (!__all(got != 0)) fast_ok = 0;   // sticky: sc0 path broken/slow
                }
                if (!__all(got != 0)) {
                    const unsigned* sp = fsD + (size_t)l*TT + (step-1);
                    for (int it=0; it<8192 && !__all(got != 0); ++it)
                        if (!got) got = __hip_atomic_load(sp, __ATOMIC_RELAXED,
                                                          __HIP_MEMORY_SCOPE_AGENT);
                    if (!__all(got != 0)) dead = 1;      // protocol failure: free-run
                }
            }
            // h_{t-1} A-frags: plain loads, step-indexed = first-touch in L1,
            // fill from shared XCD L2. lanes lrow>=8 read slack -> D rows 8..15.
            const f16* ex = ex_base + (size_t)(step-1)*3072;
            f16x8 af[12];
            #pragma unroll
            for (int kk=0;kk<12;kk++) af[kk] = *(const f16x8*)(ex + kk*256);
            #pragma unroll
            for (int kk=0;kk<12;kk++) {
                acc0 = __builtin_amdgcn_mfma_f32_16x16x32_f16(af[kk], bf[0][kk], acc0,0,0,0);
                acc1 = __builtin_amdgcn_mfma_f32_16x16x32_f16(af[kk], bf[1][kk], acc1,0,0,0);
                acc2 = __builtin_amdgcn_mfma_f32_16x16x32_f16(af[kk], bf[2][kk], acc2,0,0,0);
                acc3 = __builtin_amdgcn_mfma_f32_16x16x32_f16(af[kk], bf[3][kk], acc3,0,0,0);
            }
        }
        // in-register epilogue: lane (lgrp<2) owns (c, b=lgrp*4+r), r=0..3
        f16 hh0, hh1, hh2, hh3;
        EPI(0, pA, 0, cst0, hh0)
        EPI(1, pA, 1, cst1, hh1)
        EPI(2, pB, 0, cst2, hh2)
        EPI(3, pB, 1, cst3, hh3)

        // exch stores: even-c lane packs (c,c+1) per batch -> 4B stores
        f16* exrow = exchD + (size_t)step*3072;
        STEX(hh0, 0)
        STEX(hh1, 1)
        STEX(hh2, 2)
        STEX(hh3, 3)
        // xout before publish: acks overlap exch acks in the same vmcnt(0)
        if (lgrp < 2) {
            size_t xr = ((size_t)(lgrp*4)*TT + t)*HH + xo_base;
            xout[xr]                    = hh0;
            xout[xr + (size_t)TT*HH]    = hh1;
            xout[xr + (size_t)2*TT*HH]  = hh2;
            xout[xr + (size_t)3*TT*HH]  = hh3;
        }
        // per-wave publish: this wave's 16 cols are in L2 once vmcnt hits 0
        asm volatile("s_waitcnt vmcnt(0)" ::: "memory");
        if (l == 0) {
            ffD[(size_t)wfid*TT + step] = 1u;                       // fast copy (plain)
            __hip_atomic_store(fsD + (size_t)wfid*TT + step, 1u,
                               __ATOMIC_RELAXED, __HIP_MEMORY_SCOPE_AGENT);  // safe copy
        }
        // stage next pre chunk (once per 8 steps; drained at next poll's vmcnt(0),
        // ~7 steps before first read)
        if ((step & 7) == 0 && step + 8 < TT) {
            int s0n = step + 8;
            int tmin = dir ? (TT - 8 - s0n) : s0n;
            const f16* src = srcW + (size_t)tmin*512 + l*8;
            f16* dst = myLDS + ((s0n>>3)&1)*4096;
            #pragma unroll
            for (int i=0;i<8;i++)
                gload_lds16(src + i*512, dst + i*512);
        }
    }
}

// ---------------- segment mean pool + MLP + sigmoid ----------------
__global__ void pool_mlp_k(const f16* __restrict__ enc, const int* __restrict__ bounds,
                           const float* __restrict__ w1, const float* __restrict__ b1,
                           const float* __restrict__ w2, const float* __restrict__ b2,
                           float* __restrict__ out) {
    int b = blockIdx.x >> 4, s = blockIdx.x & 15;
    int tid = threadIdx.x;
    int e  = bounds[b*SS + s];
    int st = (s==0) ? 0 : bounds[b*SS + s - 1];
    int len = e - st; if (len < 1) len = 1;
    __shared__ float meanS[HH];
    __shared__ float hS[HDD];
    __shared__ float redS[256];
    for (int dd = tid; dd < HH; dd += 256) {
        float a = 0.f;
        for (int t = st; t < e; t++) a += (float)enc[((size_t)b*TT + t)*HH + dd];
        meanS[dd] = a / (float)len;
    }
    __syncthreads();
    for (int j = tid; j < HDD; j += 256) {
        float a = b1[j];
        const float* wr = w1 + (size_t)j*HH;
        for (int dd = 0; dd < HH; dd++) a += meanS[dd]*wr[dd];
        hS[j] = a > 0.f ? a : 0.f;
    }
    __syncthreads();
    float p = 0.f;
    for (int j = tid; j < HDD; j += 256) p += hS[j]*w2[j];
    redS[tid] = p;
    __syncthreads();
    for (int o = 128; o > 0; o >>= 1) {
        if (tid < o) redS[tid] += redS[tid+o];
        __syncthreads();
    }
    if (tid == 0) {
        float r = 1.f/(1.f+__expf(-(redS[0] + b2[0])));
        out[b*SS + s] = r;
    }
}

__global__ void finalize_k(float* __restrict__ out) {
    int b = threadIdx.x;
    if (b < BB) {
        float m = 1e30f;
        for (int s=0;s<SS;s++) {
            float r = out[b*SS+s];
            float mask = (r > 0.f) ? 1.f : 0.f;
            float v = r*mask + (1.f-mask);
            m = fminf(m, v);
        }
        out[BB*SS + b] = m;
    }
}

extern "C" void kernel_launch(void* const* d_in, const int* in_sizes, int n_in,
                              void* d_out, int out_size, void* d_ws, size_t ws_size,
                              hipStream_t stream) {
    const int*   ids    = (const int*)d_in[0];
    const int*   bounds = (const int*)d_in[1];
    const float* emb    = (const float*)d_in[2];
    const float* wih[4]; const float* whh[4]; const float* bih[4]; const float* bhh[4];
    for (int i=0;i<4;i++) {                // order: l0f, l0b, l1f, l1b
        wih[i] = (const float*)d_in[3 + 4*i];
        whh[i] = (const float*)d_in[4 + 4*i];
        bih[i] = (const float*)d_in[5 + 4*i];
        bhh[i] = (const float*)d_in[6 + 4*i];
    }
    const float* w1 = (const float*)d_in[19];
    const float* b1 = (const float*)d_in[20];
    const float* w2 = (const float*)d_in[21];
    const float* b2 = (const float*)d_in[22];
    float* out = (float*)d_out;

    char* ws = (char*)d_ws;
    size_t off = 0;
    auto alloc = [&](size_t bytes) -> void* {
        void* p = ws + off;
        off += (bytes + 255) & ~(size_t)255;
        return p;
    };
    f16* x0    = (f16*)alloc((size_t)MTOT*HH*2);      // layer0 input; reused as enc
    f16* x1    = (f16*)alloc((size_t)MTOT*HH*2);      // layer0 output / layer1 input
    f16* pre   = (f16*)alloc((size_t)2*MTOT*NG*2);    // pre-activations (reused per layer)
    f16* exch  = (f16*)alloc((size_t)2*TT*3072*2 + 4096); // h exchange (+tail-read slack)
    f16* wihh[4]; for (int i=0;i<4;i++) wihh[i] = (f16*)alloc((size_t)NG*HH*2);
    f16* whhh[4]; for (int i=0;i<4;i++) whhh[i] = (f16*)alloc((size_t)NG*HDD*2);
    float* bsum = (float*)alloc((size_t)4*NG*4);
    // flags (fast + safe): [layer][dir][producer wave 0..23][t]
    unsigned* flags_fast = (unsigned*)alloc((size_t)2*2*24*TT*4);
    unsigned* flags_safe = (unsigned*)alloc((size_t)2*2*24*TT*4);
    unsigned* elect      = (unsigned*)alloc((size_t)2*16*4);
    f16* enc = x0;

    hipMemsetAsync(flags_fast, 0, (size_t)2*2*24*TT*4, stream);
    hipMemsetAsync(flags_safe, 0, (size_t)2*2*24*TT*4, stream);
    hipMemsetAsync(elect,      0, (size_t)2*16*4, stream);
    for (int i=0;i<4;i++)
        cast_f32_f16_k<<<(NG*HH+255)/256,256,0,stream>>>(wih[i], wihh[i], NG*HH);
    for (int i=0;i<4;i++)
        cast_f32_f16_k<<<(NG*HDD+255)/256,256,0,stream>>>(whh[i], whhh[i], NG*HDD);
    bias_sum_k<<<(4*NG+255)/256,256,0,stream>>>(bih[0],bhh[0],bih[1],bhh[1],
                                                bih[2],bhh[2],bih[3],bhh[3],bsum);
    embed_cast_k<<<(MTOT*HH+255)/256,256,0,stream>>>(ids, emb, x0);

    dim3 gg(MTOT/64, NG/64, 2);
    gemm_pre_k<<<gg,256,0,stream>>>(x0, wihh[0], wihh[1], bsum, pre);
    lstm_layer_k<<<256,256,0,stream>>>(pre, whhh[0], whhh[1], x1, exch,
                                       flags_fast, flags_safe, elect);
    gemm_pre_k<<<gg,256,0,stream>>>(x1, wihh[2], wihh[3], bsum + 2*NG, pre);
    lstm_layer_k<<<256,256,0,stream>>>(pre, whhh[2], whhh[3], enc, exch,
                                       flags_fast + 2*24*TT, flags_safe + 2*24*TT,
                                       elect + 16);
    pool_mlp_k<<<BB*SS,256,0,stream>>>(enc, bounds, w1, b1, w2, b2, out);
    finalize_k<<<1,64,0,stream>>>(out);
}

// Round 2
// 7176.031 us; speedup vs baseline: 1.2421x; 1.2421x over previous
//
#include <hip/hip_runtime.h>

typedef _Float16 f16;
typedef _Float16 f16x4 __attribute__((ext_vector_type(4)));
typedef _Float16 f16x8 __attribute__((ext_vector_type(8)));
typedef float f32x4 __attribute__((ext_vector_type(4)));

#define BB 8
#define TT 1024
#define HH 768
#define HDD 384
#define NG 1536        // 4*HDD
#define SS 16
#define MTOT (BB*TT)   // 8192

// ---------------- casts ----------------
__global__ void cast_f32_f16_k(const float* __restrict__ src, f16* __restrict__ dst, int n) {
    int i = blockIdx.x*256 + threadIdx.x;
    if (i < n) dst[i] = (f16)src[i];
}

__global__ void bias_sum_k(const float* a0,const float* b0,const float* a1,const float* b1,
                           const float* a2,const float* b2,const float* a3,const float* b3,
                           float* __restrict__ out) {
    int i = blockIdx.x*256 + threadIdx.x;
    if (i >= 4*NG) return;
    int which = i/NG, j = i - which*NG;
    const float* pa = which==0?a0:which==1?a1:which==2?a2:a3;
    const float* pb = which==0?b0:which==1?b1:which==2?b2:b3;
    out[i] = pa[j] + pb[j];
}

__global__ void embed_cast_k(const int* __restrict__ ids, const float* __restrict__ emb,
                             f16* __restrict__ x) {
    int i = blockIdx.x*256 + threadIdx.x;   // < MTOT*HH
    if (i < MTOT*HH) {
        int m = i / HH;
        int k = i - m*HH;
        x[i] = (f16)emb[(size_t)ids[m]*HH + k];
    }
}

// ---------------- input GEMM ----------------
// R6 layout (validated): pre[dir][wb][t][lc][b][gate], wb=c/16 (0..23),
// lc=c%16, b=batch, gate=0..3 -> per (wb,t): 512 f16 = 1KB contiguous.
// Enables bulk global_load_lds staging in the LSTM kernel.
__launch_bounds__(256,1)
__global__ void gemm_pre_k(const f16* __restrict__ A, const f16* __restrict__ Wf,
                           const f16* __restrict__ Wb, const float* __restrict__ bsum2,
                           f16* __restrict__ pre) {
    int d = blockIdx.z;
    const f16* Wt = d ? Wb : Wf;
    const float* bs = bsum2 + d*NG;
    f16* out = pre + (size_t)d*MTOT*NG;
    int m0 = blockIdx.x*64, n0 = blockIdx.y*64;
    __shared__ f16 As[64*72];
    __shared__ f16 Bs[64*72];
    int tid = threadIdx.x;
    int w = tid>>6, l = tid&63;
    int lrow = l&15, lgrp = l>>4;
    int mq = (w>>1)*32, nq = (w&1)*32;
    f32x4 acc00={0,0,0,0}, acc01={0,0,0,0}, acc10={0,0,0,0}, acc11={0,0,0,0};

    for (int k0=0; k0<HH; k0+=64) {
        __syncthreads();
        #pragma unroll
        for (int r=0;r<2;r++) {
            int c = tid + 256*r;
            int row = c>>3, seg = c&7;
            *(f16x8*)(As + row*72 + seg*8) = *(const f16x8*)(A  + ((size_t)(m0+row))*HH + k0 + seg*8);
            *(f16x8*)(Bs + row*72 + seg*8) = *(const f16x8*)(Wt + ((size_t)(n0+row))*HH + k0 + seg*8);
        }
        __syncthreads();
        #pragma unroll
        for (int kk=0; kk<64; kk+=32) {
            f16x8 a0 = *(const f16x8*)(As + (mq+lrow)*72    + kk + lgrp*8);
            f16x8 a1 = *(const f16x8*)(As + (mq+16+lrow)*72 + kk + lgrp*8);
            f16x8 b0 = *(const f16x8*)(Bs + (nq+lrow)*72    + kk + lgrp*8);
            f16x8 b1 = *(const f16x8*)(Bs + (nq+16+lrow)*72 + kk + lgrp*8);
            acc00 = __builtin_amdgcn_mfma_f32_16x16x32_f16(a0,b0,acc00,0,0,0);
            acc01 = __builtin_amdgcn_mfma_f32_16x16x32_f16(a0,b1,acc01,0,0,0);
            acc10 = __builtin_amdgcn_mfma_f32_16x16x32_f16(a1,b0,acc10,0,0,0);
            acc11 = __builtin_amdgcn_mfma_f32_16x16x32_f16(a1,b1,acc11,0,0,0);
        }
    }
    #pragma unroll
    for (int mt=0;mt<2;mt++) {
        #pragma unroll
        for (int nt=0;nt<2;nt++) {
            f32x4 a = (mt==0)?(nt==0?acc00:acc01):(nt==0?acc10:acc11);
            int col = n0 + nq + nt*16 + lrow;     // 0..1535 = gate*384 + c
            int gate = col / HDD;
            int c = col - gate*HDD;               // 0..383
            float bv = bs[col];
            size_t base = (size_t)(c>>4)*524288 + (size_t)(c&15)*32 + gate;
            #pragma unroll
            for (int r=0;r<4;r++) {
                int row = m0 + mq + mt*16 + lgrp*4 + r;   // b*1024 + t
                int b = row >> 10, t = row & 1023;
                out[base + (size_t)t*512 + b*4] = (f16)(a[r] + bv);
            }
        }
    }
}

// ---- helpers ----
__device__ __forceinline__ unsigned ld_u32_sc0(const unsigned* p) {
    unsigned v;
    asm volatile("global_load_dword %0, %1, off sc0\n\ts_waitcnt vmcnt(0)"
                 : "=v"(v) : "v"(p) : "memory");
    return v;
}
__device__ __forceinline__ unsigned get_xcc() {
    unsigned x;
    asm("s_getreg_b32 %0, hwreg(HW_REG_XCC_ID)" : "=s"(x));
    return x & 7u;
}
__device__ __forceinline__ void gload_lds16(const f16* g, f16* lds) {
    // wave-uniform LDS dest (HW adds lane*16B); per-lane global src
    __builtin_amdgcn_global_load_lds(
        (const __attribute__((address_space(1))) void*)g,
        (__attribute__((address_space(3))) void*)lds, 16, 0, 0);
}

// ---------------- LSTM recurrence ----------------
// R7: R5 structure (24 blocks, wave=gate, 96 waves — the validated 3750us
// protocol) + three targeted changes:
//  1) pre staged into LDS in 8-step/16KB per-block double-buffered chunks via
//     global_load_lds (R6 layout). Per-step pre access = one ds_read_b64
//     (lgkmcnt) -> the poll's vmcnt(0) no longer drains L3 latency every step;
//     the staging drain hits one poll per 8 steps (amortized ~1/8).
//     Cross-wave staging visibility: staged at end of step s, first read at
//     step s+8; each wave's own poll-vmcnt(0) + the per-step barriers order it.
//  2) xout stores moved AFTER the flag publish — their ACK latency comes off
//     the publish path (hides under the next step's poll).
//  3) non-elected blocks = DPM fillers: low-power dependent-FMA spin, polling
//     a done-counter (elect[10]) every ~16K cycles, capped. Keeps all CUs busy
//     so clocks stay up for this latency-bound chain. LDS padded >80KB pins
//     1 block/CU (no filler co-residency with producers).
__launch_bounds__(256,1)
__global__ void lstm_layer_k(const f16* __restrict__ pre,
                             const f16* __restrict__ whh_f,
                             const f16* __restrict__ whh_b,
                             f16* __restrict__ xout,
                             f16* __restrict__ exch,
                             unsigned* __restrict__ flags_fast,
                             unsigned* __restrict__ flags_safe,
                             unsigned* __restrict__ elect) {
    int tid = threadIdx.x;
    __shared__ unsigned role_s;
    __shared__ f16 preS[40960];       // 80KB declared (32KB used) -> 1 block/CU
    __shared__ float gatesS[128*9];   // [local col][batch], stride 9 conflict-free
    if (tid == 0) {
        unsigned xcc = get_xcc();
        unsigned r = __hip_atomic_fetch_add(&elect[xcc], 1u,
                        __ATOMIC_RELAXED, __HIP_MEMORY_SCOPE_AGENT);
        if (r == 23u) {                      // this XCD just reached 24 running blocks
            unsigned expected = 0u;
            __hip_atomic_compare_exchange_strong(&elect[8], &expected, xcc + 1u,
                __ATOMIC_RELAXED, __ATOMIC_RELAXED, __HIP_MEMORY_SCOPE_AGENT);
        }
        unsigned win = 0;
        for (int it = 0; it < (1<<20) && !win; ++it) {   // capped: no hang possible
            win = __hip_atomic_load(&elect[8], __ATOMIC_RELAXED, __HIP_MEMORY_SCOPE_AGENT);
            if (!win) __builtin_amdgcn_s_sleep(8);
        }
        unsigned role = 0xFFFFFFFFu;
        if (win == xcc + 1u)
            role = __hip_atomic_fetch_add(&elect[9], 1u,
                        __ATOMIC_RELAXED, __HIP_MEMORY_SCOPE_AGENT);
        role_s = role;
    }
    __syncthreads();
    unsigned role = role_s;
    if (role >= 24u) {
        // ---- filler: hold DPM clocks up until producers finish (capped) ----
        float a0 = (float)tid, a1 = a0 + 1.f;
        for (int body = 0; body < (1<<16); ++body) {
            #pragma unroll
            for (int k = 0; k < 32; ++k) {
                a0 = __builtin_fmaf(a0, 0.99993896f, 1.52587891e-5f);
                a1 = __builtin_fmaf(a1, 0.99993896f, 3.05175781e-5f);
            }
            if ((body & 63) == 0) {
                if (__hip_atomic_load(&elect[10], __ATOMIC_RELAXED,
                                      __HIP_MEMORY_SCOPE_AGENT) >= 24u) break;
            }
        }
        asm volatile("" :: "v"(a0), "v"(a1));   // keep spin live
        return;
    }

    int dir = role >= 12u;
    int g   = (int)role - dir*12;
    const f16* W    = dir ? whh_b : whh_f;
    const f16* preD = pre  + (size_t)dir*MTOT*NG;
    f16* exchD      = exch + (size_t)dir*TT*3072;
    unsigned* ffD = flags_fast + dir*12*TT;
    unsigned* fsD = flags_safe + dir*12*TT;

    int w = tid>>6, l = tid&63;       // wave w == gate index (i,f,g,o)
    int lrow = l&15, lgrp = l>>4;

    // register-resident W_hh B-frags: rows = w*384 + 32g + {0..31}
    f16x8 bf0[12], bf1[12];
    {
        int row0 = w*HDD + g*32 + lrow;
        #pragma unroll
        for (int kk=0; kk<12; kk++)
            bf0[kk] = *(const f16x8*)(W + (size_t)row0*HDD + kk*32 + lgrp*8);
        int row1 = row0 + 16;
        #pragma unroll
        for (int kk=0; kk<12; kk++)
            bf1[kk] = *(const f16x8*)(W + (size_t)row1*HDD + kk*32 + lgrp*8);
    }

    int eb = tid>>5, ejh = tid&31;    // epilogue thread = (batch, jh)
    float c_state = 0.f;
    size_t exch_wr = ((size_t)g*4 + (ejh>>3))*64 + (size_t)eb*8 + (ejh&7);
    size_t mrow = (size_t)eb*TT;
    const f16* ex_base = exchD + (size_t)lgrp*64 + (size_t)lrow*8;

    // pre staging: block g owns col-blocks wb=2g (wh=0), 2g+1 (wh=1)
    const f16* preB0 = preD + (size_t)(2*g    )*524288;
    const f16* preB1 = preD + (size_t)(2*g + 1)*524288;
    int su = w*4;                     // this wave's first staging unit (of 16)
    const f16* pread = preS + (size_t)(ejh>>4)*512 + (size_t)(ejh&15)*32 + (size_t)eb*4;

    {   // prologue: stage chunk for steps 0..7 into buf 0
        int tmin = dir ? (TT-8) : 0;
        #pragma unroll
        for (int i=0;i<4;i++) {
            int u = su + i, wh = u>>3, slot = u&7;
            const f16* src = (wh ? preB1 : preB0) + (size_t)(tmin+slot)*512 + l*8;
            gload_lds16(src, preS + slot*1024 + wh*512);
        }
        asm volatile("s_waitcnt vmcnt(0)" ::: "memory");
    }
    __syncthreads();                  // staged chunk visible to all waves

    int fast_ok = 1, dead = 0;        // wave-uniform sticky state

    for (int step=0; step<TT; step++) {
        int t = dir ? (TT-1-step) : step;
        int slot = dir ? (7-(step&7)) : (step&7);   // LDS holds t-ascending
        int buf = (step>>3)&1;
        // pre from LDS: 4 gates for this (batch,col) in one 8B ds_read
        f16x4 pv = *(const f16x4*)(pread + buf*8192 + slot*1024);

        f32x4 acc0 = {0,0,0,0}, acc1 = {0,0,0,0};
        if (step > 0) {
            unsigned got = (l < 12) ? 0u : 1u;
            if (!dead) {
                if (fast_ok) {
                    const unsigned* fp = ffD + (size_t)l*TT + (step-1);
                    for (int it=0; it<1024 && !__all(got != 0); ++it)
                        if (!got) got = ld_u32_sc0(fp);
                    if (!__all(got != 0)) fast_ok = 0;   // sticky: sc0 path broken/slow
                }
                if (!__all(got != 0)) {
                    const unsigned* sp = fsD + (size_t)l*TT + (step-1);
                    for (int it=0; it<8192 && !__all(got != 0); ++it)
                        if (!got) got = __hip_atomic_load(sp, __ATOMIC_RELAXED,
                                                          __HIP_MEMORY_SCOPE_AGENT);
                    if (!__all(got != 0)) dead = 1;      // protocol failure: free-run
                }
            }
            // plain data loads: first-touch in L1, fill from shared XCD L2.
            // lanes lrow>=8 read unwritten slack -> D rows 8..15, never used.
            const f16* ex = ex_base + (size_t)(step-1)*3072;
            #pragma unroll
            for (int kk=0; kk<12; kk++) {
                f16x8 af = *(const f16x8*)(ex + (size_t)kk*256);
                acc0 = __builtin_amdgcn_mfma_f32_16x16x32_f16(af, bf0[kk], acc0, 0,0,0);
                acc1 = __builtin_amdgcn_mfma_f32_16x16x32_f16(af, bf1[kk], acc1, 0,0,0);
            }
        }
        // stage gates (C layout: col=l&15, row=4*lgrp+r; rows>=8 garbage, not staged)
        if (lgrp < 2) {
            int col0 = 32*w + lrow;
            #pragma unroll
            for (int r=0;r<4;r++) gatesS[col0*9 + lgrp*4 + r] = acc0[r];
            int col1 = col0 + 16;
            #pragma unroll
            for (int r=0;r<4;r++) gatesS[col1*9 + lgrp*4 + r] = acc1[r];
        }
        __syncthreads();                               // gates visible to epilogue
        float xi = (float)pv[0] + gatesS[(ejh   )*9 + eb];
        float xf = (float)pv[1] + gatesS[(32+ejh)*9 + eb];
        float xg = (float)pv[2] + gatesS[(64+ejh)*9 + eb];
        float xo = (float)pv[3] + gatesS[(96+ejh)*9 + eb];
        float si = 1.f/(1.f+__expf(-xi));
        float sf = 1.f/(1.f+__expf(-xf));
        float eg = __expf(2.f*xg);  float gg = (eg-1.f)/(eg+1.f);
        float so = 1.f/(1.f+__expf(-xo));
        c_state = sf*c_state + si*gg;
        float ec = __expf(2.f*c_state); float tc = (ec-1.f)/(ec+1.f);
        float h = so*tc;
        f16 hh = (f16)h;
        // pack (even,odd) lane pair -> one 4B plain store (write-through to L2)
        unsigned short hu; __builtin_memcpy(&hu, &hh, 2);
        unsigned short pu = (unsigned short)__shfl_xor((int)hu, 1, 64);
        if ((ejh & 1) == 0) {
            unsigned pkt = (unsigned)hu | ((unsigned)pu << 16);
            *(unsigned*)(exchD + (size_t)step*3072 + exch_wr) = pkt;
        }
        __syncthreads();           // vmcnt(0) drain: exch stores ACKed in L2
        if (tid == 0) {
            ffD[(size_t)g*TT + step] = 1u;                       // fast copy (plain)
            __hip_atomic_store(fsD + (size_t)g*TT + step, 1u,
                               __ATOMIC_RELAXED, __HIP_MEMORY_SCOPE_AGENT);  // safe copy
        }
        // xout AFTER publish: its ACK drains at the next poll, off the
        // publish critical path
        xout[(mrow + t)*HH + dir*HDD + g*32 + ejh] = hh;
        // stage next pre chunk (once per 8 steps; drained at next poll's
        // vmcnt(0), visible to peers via subsequent barriers — 7 steps of slack)
        if ((step & 7) == 0 && step + 8 < TT) {
            int s0n = step + 8;
            int tmin = dir ? (TT - 8 - s0n) : s0n;
            f16* dstb = preS + ((s0n>>3)&1)*8192;
            #pragma unroll
            for (int i=0;i<4;i++) {
                int u = su + i, wh = u>>3, slot = u&7;
                const f16* src = (wh ? preB1 : preB0) + (size_t)(tmin+slot)*512 + l*8;
                gload_lds16(src, dstb + slot*1024 + wh*512);
            }
        }
    }
    if (tid == 0)   // release fillers
        __hip_atomic_fetch_add(&elect[10], 1u, __ATOMIC_RELAXED, __HIP_MEMORY_SCOPE_AGENT);
}

// ---------------- segment mean pool + MLP + sigmoid ----------------
__global__ void pool_mlp_k(const f16* __restrict__ enc, const int* __restrict__ bounds,
                           const float* __restrict__ w1, const float* __restrict__ b1,
                           const float* __restrict__ w2, const float* __restrict__ b2,
                           float* __restrict__ out) {
    int b = blockIdx.x >> 4, s = blockIdx.x & 15;
    int tid = threadIdx.x;
    int e  = bounds[b*SS + s];
    int st = (s==0) ? 0 : bounds[b*SS + s - 1];
    int len = e - st; if (len < 1) len = 1;
    __shared__ float meanS[HH];
    __shared__ float hS[HDD];
    __shared__ float redS[256];
    for (int dd = tid; dd < HH; dd += 256) {
        float a = 0.f;
        for (int t = st; t < e; t++) a += (float)enc[((size_t)b*TT + t)*HH + dd];
        meanS[dd] = a / (float)len;
    }
    __syncthreads();
    for (int j = tid; j < HDD; j += 256) {
        float a = b1[j];
        const float* wr = w1 + (size_t)j*HH;
        for (int dd = 0; dd < HH; dd++) a += meanS[dd]*wr[dd];
        hS[j] = a > 0.f ? a : 0.f;
    }
    __syncthreads();
    float p = 0.f;
    for (int j = tid; j < HDD; j += 256) p += hS[j]*w2[j];
    redS[tid] = p;
    __syncthreads();
    for (int o = 128; o > 0; o >>= 1) {
        if (tid < o) redS[tid] += redS[tid+o];
        __syncthreads();
    }
    if (tid == 0) {
        float r = 1.f/(1.f+__expf(-(redS[0] + b2[0])));
        out[b*SS + s] = r;
    }
}

__global__ void finalize_k(float* __restrict__ out) {
    int b = threadIdx.x;
    if (b < BB) {
        float m = 1e30f;
        for (int s=0;s<SS;s++) {
            float r = out[b*SS+s];
            float mask = (r > 0.f) ? 1.f : 0.f;
            float v = r*mask + (1.f-mask);
            m = fminf(m, v);
        }
        out[BB*SS + b] = m;
    }
}

extern "C" void kernel_launch(void* const* d_in, const int* in_sizes, int n_in,
                              void* d_out, int out_size, void* d_ws, size_t ws_size,
                              hipStream_t stream) {
    const int*   ids    = (const int*)d_in[0];
    const int*   bounds = (const int*)d_in[1];
    const float* emb    = (const float*)d_in[2];
    const float* wih[4]; const float* whh[4]; const float* bih[4]; const float* bhh[4];
    for (int i=0;i<4;i++) {                // order: l0f, l0b, l1f, l1b
        wih[i] = (const float*)d_in[3 + 4*i];
        whh[i] = (const float*)d_in[4 + 4*i];
        bih[i] = (const float*)d_in[5 + 4*i];
        bhh[i] = (const float*)d_in[6 + 4*i];
    }
    const float* w1 = (const float*)d_in[19];
    const float* b1 = (const float*)d_in[20];
    const float* w2 = (const float*)d_in[21];
    const float* b2 = (const float*)d_in[22];
    float* out = (float*)d_out;

    char* ws = (char*)d_ws;
    size_t off = 0;
    auto alloc = [&](size_t bytes) -> void* {
        void* p = ws + off;
        off += (bytes + 255) & ~(size_t)255;
        return p;
    };
    f16* x0    = (f16*)alloc((size_t)MTOT*HH*2);      // layer0 input; reused as enc
    f16* x1    = (f16*)alloc((size_t)MTOT*HH*2);      // layer0 output / layer1 input
    f16* pre   = (f16*)alloc((size_t)2*MTOT*NG*2);    // pre-activations (reused per layer)
    f16* exch  = (f16*)alloc((size_t)2*TT*3072*2 + 4096); // h exchange (+tail-read slack)
    f16* wihh[4]; for (int i=0;i<4;i++) wihh[i] = (f16*)alloc((size_t)NG*HH*2);
    f16* whhh[4]; for (int i=0;i<4;i++) whhh[i] = (f16*)alloc((size_t)NG*HDD*2);
    float* bsum = (float*)alloc((size_t)4*NG*4);
    // flags (fast + safe): [layer][dir][producer g][t], g-stride 4KB
    unsigned* flags_fast = (unsigned*)alloc((size_t)2*2*12*TT*4);
    unsigned* flags_safe = (unsigned*)alloc((size_t)2*2*12*TT*4);
    unsigned* elect      = (unsigned*)alloc((size_t)2*16*4);
    f16* enc = x0;

    hipMemsetAsync(flags_fast, 0, (size_t)2*2*12*TT*4, stream);
    hipMemsetAsync(flags_safe, 0, (size_t)2*2*12*TT*4, stream);
    hipMemsetAsync(elect,      0, (size_t)2*16*4, stream);
    for (int i=0;i<4;i++)
        cast_f32_f16_k<<<(NG*HH+255)/256,256,0,stream>>>(wih[i], wihh[i], NG*HH);
    for (int i=0;i<4;i++)
        cast_f32_f16_k<<<(NG*HDD+255)/256,256,0,stream>>>(whh[i], whhh[i], NG*HDD);
    bias_sum_k<<<(4*NG+255)/256,256,0,stream>>>(bih[0],bhh[0],bih[1],bhh[1],
                                                bih[2],bhh[2],bih[3],bhh[3],bsum);
    embed_cast_k<<<(MTOT*HH+255)/256,256,0,stream>>>(ids, emb, x0);

    dim3 gg(MTOT/64, NG/64, 2);
    gemm_pre_k<<<gg,256,0,stream>>>(x0, wihh[0], wihh[1], bsum, pre);
    lstm_layer_k<<<256,256,0,stream>>>(pre, whhh[0], whhh[1], x1, exch,
                                       flags_fast, flags_safe, elect);
    gemm_pre_k<<<gg,256,0,stream>>>(x1, wihh[2], wihh[3], bsum + 2*NG, pre);
    lstm_layer_k<<<256,256,0,stream>>>(pre, whhh[2], whhh[3], enc, exch,
                                       flags_fast + 2*12*TT, flags_safe + 2*12*TT,
                                       elect + 16);
    pool_mlp_k<<<BB*SS,256,0,stream>>>(enc, bounds, w1, b1, w2, b2, out);
    finalize_k<<<1,64,0,stream>>>(out);
}